// Round 12
// baseline (214.961 us; speedup 1.0000x reference)
//
#include <hip/hip_runtime.h>

typedef unsigned int uint;
typedef unsigned short ushort;
typedef short s8v __attribute__((ext_vector_type(8)));   // 8 bf16 (4 VGPRs)
typedef float f4v __attribute__((ext_vector_type(4)));   // 4 f32 acc

#define BSHIFT 8                 // 256 nodes per bucket
#define NBUCK_MAX 512
#define PART_CH 16384            // edges per partition block
#define GS_CH 2048               // generic scan chunk

// ---------------- bf16 helpers ----------------

__device__ __forceinline__ uint f2bf(float f) {       // RNE round to bf16, low 16
    uint b = __float_as_uint(f);
    return (b + 0x7fffu + ((b >> 16) & 1u)) >> 16;
}
__device__ __forceinline__ uint pack2(float a, float b) {
    return f2bf(a) | (f2bf(b) << 16);
}
__device__ __forceinline__ float bflo(uint u) { return __uint_as_float(u << 16); }
__device__ __forceinline__ float bfhi(uint u) { return __uint_as_float(u & 0xffff0000u); }

// ---------------- CSR build: single histogram + exact-offset partition ----------------

// per-chunk bucket histogram, stored bin-major: cnt_blk[bucket * PB + blk]
__global__ __launch_bounds__(256) void hist2_k(const int* __restrict__ dst, int E, int nbuck,
                                               int PB, int* __restrict__ cnt_blk) {
    __shared__ int h[NBUCK_MAX];
    int t = threadIdx.x;
    for (int i = t; i < nbuck; i += 256) h[i] = 0;
    __syncthreads();
    int e0 = blockIdx.x * PART_CH;
    int e1 = min(e0 + PART_CH, E);
    for (int e = e0 + t; e < e1; e += 256) atomicAdd(&h[((uint)dst[e]) >> BSHIFT], 1);
    __syncthreads();
    for (int i = t; i < nbuck; i += 256) cnt_blk[i * PB + blockIdx.x] = h[i];
}

// ---------------- generic exclusive scan (3 kernels) ----------------

__global__ __launch_bounds__(256) void gs1_k(const int* __restrict__ in, int M,
                                             int* __restrict__ bs) {
    __shared__ int sd[256];
    int base = blockIdx.x * GS_CH;
    int sum = 0;
    for (int i = threadIdx.x; i < GS_CH; i += 256) {
        int idx = base + i;
        if (idx < M) sum += in[idx];
    }
    sd[threadIdx.x] = sum;
    __syncthreads();
    for (int s = 128; s > 0; s >>= 1) {
        if (threadIdx.x < s) sd[threadIdx.x] += sd[threadIdx.x + s];
        __syncthreads();
    }
    if (threadIdx.x == 0) bs[blockIdx.x] = sd[0];
}

__global__ __launch_bounds__(512) void gs2_k(int* __restrict__ bs, int nb) {
    __shared__ int s[512];
    int t = threadIdx.x;
    int v = (t < nb) ? bs[t] : 0;
    s[t] = v;
    __syncthreads();
    for (int off = 1; off < 512; off <<= 1) {
        int x = (t >= off) ? s[t - off] : 0;
        __syncthreads();
        s[t] += x;
        __syncthreads();
    }
    if (t < nb) bs[t] = s[t] - v;   // exclusive
}

__global__ __launch_bounds__(256) void gs3_k(const int* __restrict__ in, int M,
                                             const int* __restrict__ bs, int* __restrict__ out) {
    __shared__ int s[256];
    int base = blockIdx.x * GS_CH;
    int t = threadIdx.x;
    int loc[8];
    int sum = 0;
#pragma unroll
    for (int i = 0; i < 8; ++i) {
        int idx = base + t * 8 + i;
        int c = (idx < M) ? in[idx] : 0;
        loc[i] = sum;
        sum += c;
    }
    s[t] = sum;
    __syncthreads();
    int inc = sum;
    for (int off = 1; off < 256; off <<= 1) {
        int x = (t >= off) ? s[t - off] : 0;
        __syncthreads();
        s[t] += x;
        __syncthreads();
    }
    int toff = s[t] - inc + bs[blockIdx.x];
#pragma unroll
    for (int i = 0; i < 8; ++i) {
        int idx = base + t * 8 + i;
        if (idx < M) out[idx] = toff + loc[i];
    }
}

// place edges with exact per-(bucket, blk) offsets; LDS cursors only
__global__ __launch_bounds__(256) void part2_k(const int* __restrict__ src,
                                               const int* __restrict__ dst, int E, int nbuck,
                                               int PB, const int* __restrict__ off_blk,
                                               uint* __restrict__ eb) {
    __shared__ int cur[NBUCK_MAX];
    int t = threadIdx.x;
    int blk = blockIdx.x;
    for (int i = t; i < nbuck; i += 256) cur[i] = off_blk[i * PB + blk];
    __syncthreads();
    int e0 = blk * PART_CH;
    int e1 = min(e0 + PART_CH, E);
    for (int e = e0 + t; e < e1; e += 256) {
        int d = dst[e];
        int b = ((uint)d) >> BSHIFT;
        int p = atomicAdd(&cur[b], 1);           // LDS atomic: cheap
        eb[p] = ((uint)src[e] << BSHIFT) | (uint)(d & 255);
    }
}

// one block per bucket: per-node counts, rowptr, dinv, and CSR fill
// bucket bounds come straight from off_blk (beg = off_blk[b*PB], end = next bucket's)
__global__ __launch_bounds__(256) void build_k(const uint* __restrict__ eb,
                                               const int* __restrict__ off_blk,
                                               int PB, int nbuck, int N, int E,
                                               int* __restrict__ rowptr,
                                               float* __restrict__ dinv,
                                               int* __restrict__ csr) {
    __shared__ int c[256];
    __shared__ int s[256];
    int b = blockIdx.x;
    int t = threadIdx.x;
    int node0 = b << BSHIFT;
    int beg = off_blk[b * PB];
    int end = (b + 1 < nbuck) ? off_blk[(b + 1) * PB] : E;
    c[t] = 0;
    __syncthreads();
    for (int e = beg + t; e < end; e += 256) atomicAdd(&c[eb[e] & 255], 1);
    __syncthreads();
    int v = c[t];
    s[t] = v;
    __syncthreads();
    for (int off = 1; off < 256; off <<= 1) {
        int x = (t >= off) ? s[t - off] : 0;
        __syncthreads();
        s[t] += x;
        __syncthreads();
    }
    int excl = s[t] - v;
    int node = node0 + t;
    if (node < N) {
        rowptr[node] = beg + excl;
        dinv[node] = rsqrtf((float)(1 + v));
    }
    if (b == 0 && t == 0) rowptr[N] = E;
    __syncthreads();
    c[t] = beg + excl;                 // reuse as absolute cursor per node
    __syncthreads();
    for (int e = beg + t; e < end; e += 256) {
        uint pk = eb[e];
        int p = atomicAdd(&c[pk & 255], 1);    // LDS atomic
        csr[p] = (int)(pk >> BSHIFT);
    }
}

// ---------------- W transpose+convert (both weights, one launch) ----------------
// block 0: W1 cols 0-63; block 1: W1 cols 64-127; block 2: W2 cols 0-63

__global__ void wtrans_all_k(const float* __restrict__ W1, const float* __restrict__ W2,
                             ushort* __restrict__ Wt1, ushort* __restrict__ Wt2) {
    int blk = blockIdx.x;
    const float* W;
    ushort* Wt;
    int c, outc;
    if (blk < 2) { W = W1; Wt = Wt1; outc = 128; c = blk * 64 + threadIdx.x; }
    else         { W = W2; Wt = Wt2; outc = 64;  c = threadIdx.x; }
    if (c >= outc) return;
    for (int k0 = 0; k0 < 128; k0 += 8) {
        float v[8];
#pragma unroll
        for (int i = 0; i < 8; ++i) v[i] = W[(size_t)(k0 + i) * outc + c];
        uint4 p;
        p.x = pack2(v[0], v[1]);
        p.y = pack2(v[2], v[3]);
        p.z = pack2(v[4], v[5]);
        p.w = pack2(v[6], v[7]);
        *(uint4*)(Wt + (size_t)c * 128 + k0) = p;
    }
}

// ---------------- MFMA GEMM: hs[N x OUTC](bf16, row-major) = dinv[row]*(A[N x 128] @ W) ----

template <int OUTC, bool AF32>
__global__ __launch_bounds__(256) void gemm_mfma(const void* __restrict__ Ain,
                                                 const ushort* __restrict__ Wt,
                                                 const float* __restrict__ dinv,
                                                 ushort* __restrict__ hs, int N) {
    constexpr int NT = OUTC / 16;
    constexpr int LDK = 136;
    __shared__ ushort Al[64 * LDK];
    __shared__ ushort Wl[OUTC * LDK];

    int tid = threadIdx.x;
    int row0 = blockIdx.x * 64;

    {
        int r = tid >> 2, seg = tid & 3;
        int gr = row0 + r;
        if (gr > N - 1) gr = N - 1;
        ushort* dstp = &Al[r * LDK + seg * 32];
        if (AF32) {
            const float4* ap = (const float4*)((const float*)Ain + (size_t)gr * 128 + seg * 32);
#pragma unroll
            for (int i = 0; i < 4; ++i) {
                float4 f0 = ap[2 * i], f1 = ap[2 * i + 1];
                uint4 u;
                u.x = pack2(f0.x, f0.y);
                u.y = pack2(f0.z, f0.w);
                u.z = pack2(f1.x, f1.y);
                u.w = pack2(f1.z, f1.w);
                *(uint4*)(dstp + i * 8) = u;
            }
        } else {
            const uint4* ap = (const uint4*)((const ushort*)Ain + (size_t)gr * 128 + seg * 32);
#pragma unroll
            for (int i = 0; i < 4; ++i) *(uint4*)(dstp + i * 8) = ap[i];
        }
    }
    {
        const uint4* wp = (const uint4*)Wt;
        for (int idx = tid; idx < OUTC * 16; idx += 256) {
            int r = idx >> 4, c = idx & 15;
            *(uint4*)(&Wl[r * LDK + c * 8]) = wp[idx];
        }
    }
    __syncthreads();

    int w = tid >> 6;
    int l = tid & 63;
    int lo = l & 15, q = l >> 4;

    f4v acc[NT];
#pragma unroll
    for (int i = 0; i < NT; ++i) acc[i] = (f4v){0.f, 0.f, 0.f, 0.f};

#pragma unroll
    for (int ks = 0; ks < 4; ++ks) {
        s8v af = *(const s8v*)&Al[(16 * w + lo) * LDK + ks * 32 + q * 8];
#pragma unroll
        for (int nt = 0; nt < NT; ++nt) {
            s8v wf = *(const s8v*)&Wl[(nt * 16 + lo) * LDK + ks * 32 + q * 8];
            acc[nt] = __builtin_amdgcn_mfma_f32_16x16x32_bf16(wf, af, acc[nt], 0, 0, 0);
        }
    }

    int grow = row0 + 16 * w + lo;
    if (grow < N) {
        float dr = dinv[grow];
        ushort* orow = hs + (size_t)grow * OUTC + q * 4;
#pragma unroll
        for (int nt = 0; nt < NT; ++nt) {
            uint2 p;
            p.x = pack2(acc[nt][0] * dr, acc[nt][1] * dr);
            p.y = pack2(acc[nt][2] * dr, acc[nt][3] * dr);
            *(uint2*)(orow + nt * 16) = p;
        }
    }
}

// ---------------- fused agg1 + gemm2 ----------------
// Phase A (C=128 aggregate, 16 nodes/block):
//   h1a_row = relu(dinv[i]*(hs1[i] + sum_j hs1[j]) + b1)       (f32, regs)
// Phase B: round h1a to bf16 into LDS (MFMA B-operand layout), barrier,
//   4 waves x 4 MFMAs: hs2[i] = bf16(dinv[i] * (h1a_row @ W2))  -> [N][64]

__global__ __launch_bounds__(256) void agg1_fused_k(const ushort* __restrict__ hs,
                                                    const float* __restrict__ dinv,
                                                    const int* __restrict__ rowptr,
                                                    const int* __restrict__ csr,
                                                    const float* __restrict__ b1,
                                                    const ushort* __restrict__ wt2,
                                                    ushort* __restrict__ hs2, int N) {
    constexpr int LDK2 = 136;
    __shared__ ushort rows[16 * LDK2];   // 16 h1a rows, bf16, padded
    __shared__ ushort Wl2[64 * LDK2];    // W2^T (64 outcols x 128 K), padded
    __shared__ float dinvv[16];

    int tid = threadIdx.x;
    // stage Wt2 (L2-resident broadcast)
    {
        const uint4* wp = (const uint4*)wt2;
        for (int idx = tid; idx < 64 * 16; idx += 256) {
            int r = idx >> 4, c = idx & 15;
            *(uint4*)(&Wl2[r * LDK2 + c * 8]) = wp[idx];
        }
    }

    int sub = tid >> 4;        // node slot 0..15
    int lane = tid & 15;       // 16B (8 bf16) per lane
    int node = blockIdx.x * 16 + sub;
    bool valid = node < N;

    const uint4* h4 = (const uint4*)hs;
    float accA[8], accB[8];
#pragma unroll
    for (int k = 0; k < 8; ++k) { accA[k] = 0.f; accB[k] = 0.f; }
    float di = 0.f;
    int e = 0, end = 0;
    if (valid) {
        di = dinv[node];
        e = rowptr[node];
        end = rowptr[node + 1];
        uint4 v = h4[(size_t)node * 16 + lane];   // self term
        accA[0] = bflo(v.x); accA[1] = bfhi(v.x);
        accA[2] = bflo(v.y); accA[3] = bfhi(v.y);
        accA[4] = bflo(v.z); accA[5] = bfhi(v.z);
        accA[6] = bflo(v.w); accA[7] = bfhi(v.w);
    }

    for (; e + 8 <= end; e += 8) {
        int j[8];
#pragma unroll
        for (int k = 0; k < 8; ++k) j[k] = csr[e + k];
        uint4 v[8];
#pragma unroll
        for (int k = 0; k < 8; ++k) v[k] = h4[(size_t)j[k] * 16 + lane];
#pragma unroll
        for (int k = 0; k < 8; ++k) {
            float* a = (k & 1) ? accB : accA;   // static -> folds
            a[0] += bflo(v[k].x); a[1] += bfhi(v[k].x);
            a[2] += bflo(v[k].y); a[3] += bfhi(v[k].y);
            a[4] += bflo(v[k].z); a[5] += bfhi(v[k].z);
            a[6] += bflo(v[k].w); a[7] += bfhi(v[k].w);
        }
    }
    if (e + 4 <= end) {
        int j0 = csr[e], j1 = csr[e + 1], j2 = csr[e + 2], j3 = csr[e + 3];
        uint4 v0 = h4[(size_t)j0 * 16 + lane];
        uint4 v1 = h4[(size_t)j1 * 16 + lane];
        uint4 v2 = h4[(size_t)j2 * 16 + lane];
        uint4 v3 = h4[(size_t)j3 * 16 + lane];
        accA[0] += bflo(v0.x) + bflo(v2.x); accA[1] += bfhi(v0.x) + bfhi(v2.x);
        accA[2] += bflo(v0.y) + bflo(v2.y); accA[3] += bfhi(v0.y) + bfhi(v2.y);
        accA[4] += bflo(v0.z) + bflo(v2.z); accA[5] += bfhi(v0.z) + bfhi(v2.z);
        accA[6] += bflo(v0.w) + bflo(v2.w); accA[7] += bfhi(v0.w) + bfhi(v2.w);
        accB[0] += bflo(v1.x) + bflo(v3.x); accB[1] += bfhi(v1.x) + bfhi(v3.x);
        accB[2] += bflo(v1.y) + bflo(v3.y); accB[3] += bfhi(v1.y) + bfhi(v3.y);
        accB[4] += bflo(v1.z) + bflo(v3.z); accB[5] += bfhi(v1.z) + bfhi(v3.z);
        accB[6] += bflo(v1.w) + bflo(v3.w); accB[7] += bfhi(v1.w) + bfhi(v3.w);
        e += 4;
    }
    for (; e < end; ++e) {
        uint4 v = h4[(size_t)csr[e] * 16 + lane];
        accA[0] += bflo(v.x); accA[1] += bfhi(v.x);
        accA[2] += bflo(v.y); accA[3] += bfhi(v.y);
        accA[4] += bflo(v.z); accA[5] += bfhi(v.z);
        accA[6] += bflo(v.w); accA[7] += bfhi(v.w);
    }

    float o[8];
    if (valid) {
        const float4* b4 = (const float4*)(b1 + lane * 8);
        float4 bb0 = b4[0], bb1 = b4[1];
        o[0] = fmaxf(fmaf(di, accA[0] + accB[0], bb0.x), 0.f);
        o[1] = fmaxf(fmaf(di, accA[1] + accB[1], bb0.y), 0.f);
        o[2] = fmaxf(fmaf(di, accA[2] + accB[2], bb0.z), 0.f);
        o[3] = fmaxf(fmaf(di, accA[3] + accB[3], bb0.w), 0.f);
        o[4] = fmaxf(fmaf(di, accA[4] + accB[4], bb1.x), 0.f);
        o[5] = fmaxf(fmaf(di, accA[5] + accB[5], bb1.y), 0.f);
        o[6] = fmaxf(fmaf(di, accA[6] + accB[6], bb1.z), 0.f);
        o[7] = fmaxf(fmaf(di, accA[7] + accB[7], bb1.w), 0.f);
    } else {
#pragma unroll
        for (int k = 0; k < 8; ++k) o[k] = 0.f;
    }

    // write bf16 row into MFMA-layout LDS
    {
        uint4 p;
        p.x = pack2(o[0], o[1]);
        p.y = pack2(o[2], o[3]);
        p.z = pack2(o[4], o[5]);
        p.w = pack2(o[6], o[7]);
        *(uint4*)(&rows[sub * LDK2 + lane * 8]) = p;
        if (lane == 0) dinvv[sub] = di;
    }
    __syncthreads();

    // Phase B: wave w computes output cols [16w, 16w+16) for all 16 rows
    int w = tid >> 6;
    int l = tid & 63;
    int lo = l & 15, q = l >> 4;
    f4v acc = (f4v){0.f, 0.f, 0.f, 0.f};
#pragma unroll
    for (int ks = 0; ks < 4; ++ks) {
        s8v af = *(const s8v*)&rows[lo * LDK2 + ks * 32 + q * 8];
        s8v wf = *(const s8v*)&Wl2[(w * 16 + lo) * LDK2 + ks * 32 + q * 8];
        acc = __builtin_amdgcn_mfma_f32_16x16x32_bf16(wf, af, acc, 0, 0, 0);
    }
    int gn = blockIdx.x * 16 + lo;     // D[m][n]: n = row = lo, m = q*4+reg
    if (gn < N) {
        float dr = dinvv[lo];
        uint2 p;
        p.x = pack2(acc[0] * dr, acc[1] * dr);
        p.y = pack2(acc[2] * dr, acc[3] * dr);
        *(uint2*)(hs2 + (size_t)gn * 64 + w * 16 + q * 4) = p;
    }
}

// ---- aggregation: out[i] = dinv[i]*(hs[i] + sum_j hs[j]) + b ----

template <int C, bool RELU, bool OUTBF>
__global__ __launch_bounds__(256) void aggregate_k(const ushort* __restrict__ hs,
                                                   const float* __restrict__ dinv,
                                                   const int* __restrict__ rowptr,
                                                   const int* __restrict__ csr,
                                                   const float* __restrict__ bias,
                                                   void* __restrict__ out, int N) {
    constexpr int LANES = C / 8;       // 16B (8 bf16) per lane
    constexpr int NPB = 256 / LANES;
    int tid = threadIdx.x;
    int sub = tid / LANES;
    int lane = tid % LANES;
    int node = blockIdx.x * NPB + sub;
    if (node >= N) return;

    const uint4* h4 = (const uint4*)hs;
    float accA[8], accB[8];
    {
        uint4 v = h4[(size_t)node * LANES + lane];
        accA[0] = bflo(v.x); accA[1] = bfhi(v.x);
        accA[2] = bflo(v.y); accA[3] = bfhi(v.y);
        accA[4] = bflo(v.z); accA[5] = bfhi(v.z);
        accA[6] = bflo(v.w); accA[7] = bfhi(v.w);
    }
#pragma unroll
    for (int k = 0; k < 8; ++k) accB[k] = 0.f;

    int e = rowptr[node];
    int end = rowptr[node + 1];
    float di = dinv[node];
    for (; e + 8 <= end; e += 8) {
        int j[8];
#pragma unroll
        for (int k = 0; k < 8; ++k) j[k] = csr[e + k];
        uint4 v[8];
#pragma unroll
        for (int k = 0; k < 8; ++k) v[k] = h4[(size_t)j[k] * LANES + lane];
#pragma unroll
        for (int k = 0; k < 8; ++k) {
            float* a = (k & 1) ? accB : accA;
            a[0] += bflo(v[k].x); a[1] += bfhi(v[k].x);
            a[2] += bflo(v[k].y); a[3] += bfhi(v[k].y);
            a[4] += bflo(v[k].z); a[5] += bfhi(v[k].z);
            a[6] += bflo(v[k].w); a[7] += bfhi(v[k].w);
        }
    }
    if (e + 4 <= end) {
        int j0 = csr[e], j1 = csr[e + 1], j2 = csr[e + 2], j3 = csr[e + 3];
        uint4 v0 = h4[(size_t)j0 * LANES + lane];
        uint4 v1 = h4[(size_t)j1 * LANES + lane];
        uint4 v2 = h4[(size_t)j2 * LANES + lane];
        uint4 v3 = h4[(size_t)j3 * LANES + lane];
        accA[0] += bflo(v0.x) + bflo(v2.x); accA[1] += bfhi(v0.x) + bfhi(v2.x);
        accA[2] += bflo(v0.y) + bflo(v2.y); accA[3] += bfhi(v0.y) + bfhi(v2.y);
        accA[4] += bflo(v0.z) + bflo(v2.z); accA[5] += bfhi(v0.z) + bfhi(v2.z);
        accA[6] += bflo(v0.w) + bflo(v2.w); accA[7] += bfhi(v0.w) + bfhi(v2.w);
        accB[0] += bflo(v1.x) + bflo(v3.x); accB[1] += bfhi(v1.x) + bfhi(v3.x);
        accB[2] += bflo(v1.y) + bflo(v3.y); accB[3] += bfhi(v1.y) + bfhi(v3.y);
        accB[4] += bflo(v1.z) + bflo(v3.z); accB[5] += bfhi(v1.z) + bfhi(v3.z);
        accB[6] += bflo(v1.w) + bflo(v3.w); accB[7] += bfhi(v1.w) + bfhi(v3.w);
        e += 4;
    }
    for (; e < end; ++e) {
        uint4 v = h4[(size_t)csr[e] * LANES + lane];
        accA[0] += bflo(v.x); accA[1] += bfhi(v.x);
        accA[2] += bflo(v.y); accA[3] += bfhi(v.y);
        accA[4] += bflo(v.z); accA[5] += bfhi(v.z);
        accA[6] += bflo(v.w); accA[7] += bfhi(v.w);
    }

    const float4* b4 = (const float4*)(bias + lane * 8);
    float4 b0 = b4[0], b1 = b4[1];
    float o[8];
    o[0] = fmaf(di, accA[0] + accB[0], b0.x);
    o[1] = fmaf(di, accA[1] + accB[1], b0.y);
    o[2] = fmaf(di, accA[2] + accB[2], b0.z);
    o[3] = fmaf(di, accA[3] + accB[3], b0.w);
    o[4] = fmaf(di, accA[4] + accB[4], b1.x);
    o[5] = fmaf(di, accA[5] + accB[5], b1.y);
    o[6] = fmaf(di, accA[6] + accB[6], b1.z);
    o[7] = fmaf(di, accA[7] + accB[7], b1.w);
    if (RELU) {
#pragma unroll
        for (int k = 0; k < 8; ++k) o[k] = fmaxf(o[k], 0.f);
    }
    if (OUTBF) {
        uint4 p;
        p.x = pack2(o[0], o[1]);
        p.y = pack2(o[2], o[3]);
        p.z = pack2(o[4], o[5]);
        p.w = pack2(o[6], o[7]);
        *(uint4*)((ushort*)out + (size_t)node * C + lane * 8) = p;
    } else {
        float* op = (float*)out + (size_t)node * C + lane * 8;
        *(float4*)op = make_float4(o[0], o[1], o[2], o[3]);
        *(float4*)(op + 4) = make_float4(o[4], o[5], o[6], o[7]);
    }
}

// ---------------- launch ----------------

extern "C" void kernel_launch(void* const* d_in, const int* in_sizes, int n_in,
                              void* d_out, int out_size, void* d_ws, size_t ws_size,
                              hipStream_t stream) {
    const float* x  = (const float*)d_in[0];
    const int*   ei = (const int*)d_in[1];
    const float* W1 = (const float*)d_in[2];
    const float* b1 = (const float*)d_in[3];
    const float* W2 = (const float*)d_in[4];
    const float* b2 = (const float*)d_in[5];
    float* out = (float*)d_out;

    const int D = 128;
    int N = in_sizes[0] / D;
    int E = in_sizes[1] / 2;
    const int* src = ei;      // edge_index[0] (sources j)
    const int* dst = ei + E;  // edge_index[1] (targets i)

    int nbuck = (N + 255) >> BSHIFT;
    int PB = (E + PART_CH - 1) / PART_CH;
    int M1 = nbuck * PB;
    int G1 = (M1 + GS_CH - 1) / GS_CH;

    char* ws = (char*)d_ws;
    size_t off = 0;
    auto alloc = [&](size_t bytes) -> void* {
        void* p = ws + off;
        off += (bytes + 255) & ~(size_t)255;
        return p;
    };
    int*    cnt_blk = (int*)alloc((size_t)M1 * 4);
    int*    off_blk = (int*)alloc((size_t)M1 * 4);
    int*    gb      = (int*)alloc(2048);                    // scan blocksums (<=512)
    int*    rowptr  = (int*)alloc((size_t)(N + 1) * 4);
    float*  dinv    = (float*)alloc((size_t)N * 4);
    uint*   eb      = (uint*)alloc((size_t)E * 4);
    int*    csr     = (int*)alloc((size_t)E * 4);
    ushort* wt1     = (ushort*)alloc((size_t)128 * 128 * 2);
    ushort* wt2     = (ushort*)alloc((size_t)64 * 128 * 2);
    ushort* hs1     = (ushort*)alloc((size_t)N * 128 * 2);  // bf16 dinv*(x@W1)
    ushort* hs2     = (ushort*)alloc((size_t)N * 64 * 2);   // bf16 dinv*(h1a@W2)

    // CSR build: 1 histogram + exact-offset partition (LDS atomics only)
    hist2_k<<<PB, 256, 0, stream>>>(dst, E, nbuck, PB, cnt_blk);
    gs1_k<<<G1, 256, 0, stream>>>(cnt_blk, M1, gb);
    gs2_k<<<1, 512, 0, stream>>>(gb, G1);
    gs3_k<<<G1, 256, 0, stream>>>(cnt_blk, M1, gb, off_blk);
    part2_k<<<PB, 256, 0, stream>>>(src, dst, E, nbuck, PB, off_blk, eb);
    build_k<<<nbuck, 256, 0, stream>>>(eb, off_blk, PB, nbuck, N, E, rowptr, dinv, csr);
    // weights (single launch)
    wtrans_all_k<<<3, 64, 0, stream>>>(W1, W2, wt1, wt2);

    // layer 1 GEMM
    gemm_mfma<128, true><<<(N + 63) / 64, 256, 0, stream>>>(x, wt1, dinv, hs1, N);
    // fused: aggregate layer 1 + ReLU + GEMM 2  ->  hs2
    agg1_fused_k<<<(N + 15) / 16, 256, 0, stream>>>(hs1, dinv, rowptr, csr, b1, wt2, hs2, N);
    // aggregate layer 2 -> out (f32)
    aggregate_k<64, false, false><<<(N + 31) / 32, 256, 0, stream>>>(hs2, dinv, rowptr, csr, b2, out, N);
}

// Round 13
// 190.374 us; speedup vs baseline: 1.1292x; 1.1292x over previous
//
#include <hip/hip_runtime.h>

typedef unsigned int uint;
typedef unsigned short ushort;
typedef short s8v __attribute__((ext_vector_type(8)));   // 8 bf16 (4 VGPRs)
typedef float f4v __attribute__((ext_vector_type(4)));   // 4 f32 acc

#define BSHIFT 8                 // 256 nodes per bucket
#define NBUCK_MAX 512
#define PART_CH 8192             // edges per partition block (196 blocks: parallelism-bound)
#define GS_CH 2048               // generic scan chunk

// ---------------- bf16 helpers ----------------

__device__ __forceinline__ uint f2bf(float f) {       // RNE round to bf16, low 16
    uint b = __float_as_uint(f);
    return (b + 0x7fffu + ((b >> 16) & 1u)) >> 16;
}
__device__ __forceinline__ uint pack2(float a, float b) {
    return f2bf(a) | (f2bf(b) << 16);
}
__device__ __forceinline__ float bflo(uint u) { return __uint_as_float(u << 16); }
__device__ __forceinline__ float bfhi(uint u) { return __uint_as_float(u & 0xffff0000u); }

// ---------------- CSR build: single histogram + exact-offset partition ----------------

// per-chunk bucket histogram, stored bin-major: cnt_blk[bucket * PB + blk]
__global__ __launch_bounds__(256) void hist2_k(const int* __restrict__ dst, int E, int nbuck,
                                               int PB, int* __restrict__ cnt_blk) {
    __shared__ int h[NBUCK_MAX];
    int t = threadIdx.x;
    for (int i = t; i < nbuck; i += 256) h[i] = 0;
    __syncthreads();
    int e0 = blockIdx.x * PART_CH;
    int e1 = min(e0 + PART_CH, E);
    for (int e = e0 + t; e < e1; e += 256) atomicAdd(&h[((uint)dst[e]) >> BSHIFT], 1);
    __syncthreads();
    for (int i = t; i < nbuck; i += 256) cnt_blk[i * PB + blockIdx.x] = h[i];
}

// ---------------- generic exclusive scan (3 kernels) ----------------

__global__ __launch_bounds__(256) void gs1_k(const int* __restrict__ in, int M,
                                             int* __restrict__ bs) {
    __shared__ int sd[256];
    int base = blockIdx.x * GS_CH;
    int sum = 0;
    for (int i = threadIdx.x; i < GS_CH; i += 256) {
        int idx = base + i;
        if (idx < M) sum += in[idx];
    }
    sd[threadIdx.x] = sum;
    __syncthreads();
    for (int s = 128; s > 0; s >>= 1) {
        if (threadIdx.x < s) sd[threadIdx.x] += sd[threadIdx.x + s];
        __syncthreads();
    }
    if (threadIdx.x == 0) bs[blockIdx.x] = sd[0];
}

__global__ __launch_bounds__(512) void gs2_k(int* __restrict__ bs, int nb) {
    __shared__ int s[512];
    int t = threadIdx.x;
    int v = (t < nb) ? bs[t] : 0;
    s[t] = v;
    __syncthreads();
    for (int off = 1; off < 512; off <<= 1) {
        int x = (t >= off) ? s[t - off] : 0;
        __syncthreads();
        s[t] += x;
        __syncthreads();
    }
    if (t < nb) bs[t] = s[t] - v;   // exclusive
}

__global__ __launch_bounds__(256) void gs3_k(const int* __restrict__ in, int M,
                                             const int* __restrict__ bs, int* __restrict__ out) {
    __shared__ int s[256];
    int base = blockIdx.x * GS_CH;
    int t = threadIdx.x;
    int loc[8];
    int sum = 0;
#pragma unroll
    for (int i = 0; i < 8; ++i) {
        int idx = base + t * 8 + i;
        int c = (idx < M) ? in[idx] : 0;
        loc[i] = sum;
        sum += c;
    }
    s[t] = sum;
    __syncthreads();
    int inc = sum;
    for (int off = 1; off < 256; off <<= 1) {
        int x = (t >= off) ? s[t - off] : 0;
        __syncthreads();
        s[t] += x;
        __syncthreads();
    }
    int toff = s[t] - inc + bs[blockIdx.x];
#pragma unroll
    for (int i = 0; i < 8; ++i) {
        int idx = base + t * 8 + i;
        if (idx < M) out[idx] = toff + loc[i];
    }
}

// place edges with exact per-(bucket, blk) offsets; LDS cursors only
__global__ __launch_bounds__(256) void part2_k(const int* __restrict__ src,
                                               const int* __restrict__ dst, int E, int nbuck,
                                               int PB, const int* __restrict__ off_blk,
                                               uint* __restrict__ eb) {
    __shared__ int cur[NBUCK_MAX];
    int t = threadIdx.x;
    int blk = blockIdx.x;
    for (int i = t; i < nbuck; i += 256) cur[i] = off_blk[i * PB + blk];
    __syncthreads();
    int e0 = blk * PART_CH;
    int e1 = min(e0 + PART_CH, E);
    for (int e = e0 + t; e < e1; e += 256) {
        int d = dst[e];
        int b = ((uint)d) >> BSHIFT;
        int p = atomicAdd(&cur[b], 1);           // LDS atomic: cheap
        eb[p] = ((uint)src[e] << BSHIFT) | (uint)(d & 255);
    }
}

// one block per bucket: per-node counts, rowptr, dinv, and CSR fill
// bucket bounds come straight from off_blk (beg = off_blk[b*PB], end = next bucket's)
__global__ __launch_bounds__(256) void build_k(const uint* __restrict__ eb,
                                               const int* __restrict__ off_blk,
                                               int PB, int nbuck, int N, int E,
                                               int* __restrict__ rowptr,
                                               float* __restrict__ dinv,
                                               int* __restrict__ csr) {
    __shared__ int c[256];
    __shared__ int s[256];
    int b = blockIdx.x;
    int t = threadIdx.x;
    int node0 = b << BSHIFT;
    int beg = off_blk[b * PB];
    int end = (b + 1 < nbuck) ? off_blk[(b + 1) * PB] : E;
    c[t] = 0;
    __syncthreads();
    for (int e = beg + t; e < end; e += 256) atomicAdd(&c[eb[e] & 255], 1);
    __syncthreads();
    int v = c[t];
    s[t] = v;
    __syncthreads();
    for (int off = 1; off < 256; off <<= 1) {
        int x = (t >= off) ? s[t - off] : 0;
        __syncthreads();
        s[t] += x;
        __syncthreads();
    }
    int excl = s[t] - v;
    int node = node0 + t;
    if (node < N) {
        rowptr[node] = beg + excl;
        dinv[node] = rsqrtf((float)(1 + v));
    }
    if (b == 0 && t == 0) rowptr[N] = E;
    __syncthreads();
    c[t] = beg + excl;                 // reuse as absolute cursor per node
    __syncthreads();
    for (int e = beg + t; e < end; e += 256) {
        uint pk = eb[e];
        int p = atomicAdd(&c[pk & 255], 1);    // LDS atomic
        csr[p] = (int)(pk >> BSHIFT);
    }
}

// ---------------- W transpose+convert (both weights, one launch) ----------------
// block 0: W1 cols 0-63; block 1: W1 cols 64-127; block 2: W2 cols 0-63

__global__ void wtrans_all_k(const float* __restrict__ W1, const float* __restrict__ W2,
                             ushort* __restrict__ Wt1, ushort* __restrict__ Wt2) {
    int blk = blockIdx.x;
    const float* W;
    ushort* Wt;
    int c, outc;
    if (blk < 2) { W = W1; Wt = Wt1; outc = 128; c = blk * 64 + threadIdx.x; }
    else         { W = W2; Wt = Wt2; outc = 64;  c = threadIdx.x; }
    if (c >= outc) return;
    for (int k0 = 0; k0 < 128; k0 += 8) {
        float v[8];
#pragma unroll
        for (int i = 0; i < 8; ++i) v[i] = W[(size_t)(k0 + i) * outc + c];
        uint4 p;
        p.x = pack2(v[0], v[1]);
        p.y = pack2(v[2], v[3]);
        p.z = pack2(v[4], v[5]);
        p.w = pack2(v[6], v[7]);
        *(uint4*)(Wt + (size_t)c * 128 + k0) = p;
    }
}

// ---------------- MFMA GEMM: hs[N x OUTC](bf16, row-major) = dinv[row]*(A[N x 128] @ W) ----

template <int OUTC, bool AF32>
__global__ __launch_bounds__(256) void gemm_mfma(const void* __restrict__ Ain,
                                                 const ushort* __restrict__ Wt,
                                                 const float* __restrict__ dinv,
                                                 ushort* __restrict__ hs, int N) {
    constexpr int NT = OUTC / 16;
    constexpr int LDK = 136;
    __shared__ ushort Al[64 * LDK];
    __shared__ ushort Wl[OUTC * LDK];

    int tid = threadIdx.x;
    int row0 = blockIdx.x * 64;

    {
        int r = tid >> 2, seg = tid & 3;
        int gr = row0 + r;
        if (gr > N - 1) gr = N - 1;
        ushort* dstp = &Al[r * LDK + seg * 32];
        if (AF32) {
            const float4* ap = (const float4*)((const float*)Ain + (size_t)gr * 128 + seg * 32);
#pragma unroll
            for (int i = 0; i < 4; ++i) {
                float4 f0 = ap[2 * i], f1 = ap[2 * i + 1];
                uint4 u;
                u.x = pack2(f0.x, f0.y);
                u.y = pack2(f0.z, f0.w);
                u.z = pack2(f1.x, f1.y);
                u.w = pack2(f1.z, f1.w);
                *(uint4*)(dstp + i * 8) = u;
            }
        } else {
            const uint4* ap = (const uint4*)((const ushort*)Ain + (size_t)gr * 128 + seg * 32);
#pragma unroll
            for (int i = 0; i < 4; ++i) *(uint4*)(dstp + i * 8) = ap[i];
        }
    }
    {
        const uint4* wp = (const uint4*)Wt;
        for (int idx = tid; idx < OUTC * 16; idx += 256) {
            int r = idx >> 4, c = idx & 15;
            *(uint4*)(&Wl[r * LDK + c * 8]) = wp[idx];
        }
    }
    __syncthreads();

    int w = tid >> 6;
    int l = tid & 63;
    int lo = l & 15, q = l >> 4;

    f4v acc[NT];
#pragma unroll
    for (int i = 0; i < NT; ++i) acc[i] = (f4v){0.f, 0.f, 0.f, 0.f};

#pragma unroll
    for (int ks = 0; ks < 4; ++ks) {
        s8v af = *(const s8v*)&Al[(16 * w + lo) * LDK + ks * 32 + q * 8];
#pragma unroll
        for (int nt = 0; nt < NT; ++nt) {
            s8v wf = *(const s8v*)&Wl[(nt * 16 + lo) * LDK + ks * 32 + q * 8];
            acc[nt] = __builtin_amdgcn_mfma_f32_16x16x32_bf16(wf, af, acc[nt], 0, 0, 0);
        }
    }

    int grow = row0 + 16 * w + lo;
    if (grow < N) {
        float dr = dinv[grow];
        ushort* orow = hs + (size_t)grow * OUTC + q * 4;
#pragma unroll
        for (int nt = 0; nt < NT; ++nt) {
            uint2 p;
            p.x = pack2(acc[nt][0] * dr, acc[nt][1] * dr);
            p.y = pack2(acc[nt][2] * dr, acc[nt][3] * dr);
            *(uint2*)(orow + nt * 16) = p;
        }
    }
}

// ---------------- fused agg1 + gemm2 ----------------
// Phase A (C=128 aggregate, 16 nodes/block):
//   h1a_row = relu(dinv[i]*(hs1[i] + sum_j hs1[j]) + b1)       (f32, regs)
// Phase B: round h1a to bf16 into LDS (MFMA B-operand layout), barrier,
//   4 waves x 4 MFMAs: hs2[i] = bf16(dinv[i] * (h1a_row @ W2))  -> [N][64]

__global__ __launch_bounds__(256) void agg1_fused_k(const ushort* __restrict__ hs,
                                                    const float* __restrict__ dinv,
                                                    const int* __restrict__ rowptr,
                                                    const int* __restrict__ csr,
                                                    const float* __restrict__ b1,
                                                    const ushort* __restrict__ wt2,
                                                    ushort* __restrict__ hs2, int N) {
    constexpr int LDK2 = 136;
    __shared__ ushort rows[16 * LDK2];   // 16 h1a rows, bf16, padded
    __shared__ ushort Wl2[64 * LDK2];    // W2^T (64 outcols x 128 K), padded
    __shared__ float dinvv[16];

    int tid = threadIdx.x;
    // stage Wt2 (L2-resident broadcast)
    {
        const uint4* wp = (const uint4*)wt2;
        for (int idx = tid; idx < 64 * 16; idx += 256) {
            int r = idx >> 4, c = idx & 15;
            *(uint4*)(&Wl2[r * LDK2 + c * 8]) = wp[idx];
        }
    }

    int sub = tid >> 4;        // node slot 0..15
    int lane = tid & 15;       // 16B (8 bf16) per lane
    int node = blockIdx.x * 16 + sub;
    bool valid = node < N;

    const uint4* h4 = (const uint4*)hs;
    float accA[8], accB[8];
#pragma unroll
    for (int k = 0; k < 8; ++k) { accA[k] = 0.f; accB[k] = 0.f; }
    float di = 0.f;
    int e = 0, end = 0;
    if (valid) {
        di = dinv[node];
        e = rowptr[node];
        end = rowptr[node + 1];
        uint4 v = h4[(size_t)node * 16 + lane];   // self term
        accA[0] = bflo(v.x); accA[1] = bfhi(v.x);
        accA[2] = bflo(v.y); accA[3] = bfhi(v.y);
        accA[4] = bflo(v.z); accA[5] = bfhi(v.z);
        accA[6] = bflo(v.w); accA[7] = bfhi(v.w);
    }

    for (; e + 8 <= end; e += 8) {
        int j[8];
#pragma unroll
        for (int k = 0; k < 8; ++k) j[k] = csr[e + k];
        uint4 v[8];
#pragma unroll
        for (int k = 0; k < 8; ++k) v[k] = h4[(size_t)j[k] * 16 + lane];
#pragma unroll
        for (int k = 0; k < 8; ++k) {
            float* a = (k & 1) ? accB : accA;   // static -> folds
            a[0] += bflo(v[k].x); a[1] += bfhi(v[k].x);
            a[2] += bflo(v[k].y); a[3] += bfhi(v[k].y);
            a[4] += bflo(v[k].z); a[5] += bfhi(v[k].z);
            a[6] += bflo(v[k].w); a[7] += bfhi(v[k].w);
        }
    }
    if (e + 4 <= end) {
        int j0 = csr[e], j1 = csr[e + 1], j2 = csr[e + 2], j3 = csr[e + 3];
        uint4 v0 = h4[(size_t)j0 * 16 + lane];
        uint4 v1 = h4[(size_t)j1 * 16 + lane];
        uint4 v2 = h4[(size_t)j2 * 16 + lane];
        uint4 v3 = h4[(size_t)j3 * 16 + lane];
        accA[0] += bflo(v0.x) + bflo(v2.x); accA[1] += bfhi(v0.x) + bfhi(v2.x);
        accA[2] += bflo(v0.y) + bflo(v2.y); accA[3] += bfhi(v0.y) + bfhi(v2.y);
        accA[4] += bflo(v0.z) + bflo(v2.z); accA[5] += bfhi(v0.z) + bfhi(v2.z);
        accA[6] += bflo(v0.w) + bflo(v2.w); accA[7] += bfhi(v0.w) + bfhi(v2.w);
        accB[0] += bflo(v1.x) + bflo(v3.x); accB[1] += bfhi(v1.x) + bfhi(v3.x);
        accB[2] += bflo(v1.y) + bflo(v3.y); accB[3] += bfhi(v1.y) + bfhi(v3.y);
        accB[4] += bflo(v1.z) + bflo(v3.z); accB[5] += bfhi(v1.z) + bfhi(v3.z);
        accB[6] += bflo(v1.w) + bflo(v3.w); accB[7] += bfhi(v1.w) + bfhi(v3.w);
        e += 4;
    }
    for (; e < end; ++e) {
        uint4 v = h4[(size_t)csr[e] * 16 + lane];
        accA[0] += bflo(v.x); accA[1] += bfhi(v.x);
        accA[2] += bflo(v.y); accA[3] += bfhi(v.y);
        accA[4] += bflo(v.z); accA[5] += bfhi(v.z);
        accA[6] += bflo(v.w); accA[7] += bfhi(v.w);
    }

    float o[8];
    if (valid) {
        const float4* b4 = (const float4*)(b1 + lane * 8);
        float4 bb0 = b4[0], bb1 = b4[1];
        o[0] = fmaxf(fmaf(di, accA[0] + accB[0], bb0.x), 0.f);
        o[1] = fmaxf(fmaf(di, accA[1] + accB[1], bb0.y), 0.f);
        o[2] = fmaxf(fmaf(di, accA[2] + accB[2], bb0.z), 0.f);
        o[3] = fmaxf(fmaf(di, accA[3] + accB[3], bb0.w), 0.f);
        o[4] = fmaxf(fmaf(di, accA[4] + accB[4], bb1.x), 0.f);
        o[5] = fmaxf(fmaf(di, accA[5] + accB[5], bb1.y), 0.f);
        o[6] = fmaxf(fmaf(di, accA[6] + accB[6], bb1.z), 0.f);
        o[7] = fmaxf(fmaf(di, accA[7] + accB[7], bb1.w), 0.f);
    } else {
#pragma unroll
        for (int k = 0; k < 8; ++k) o[k] = 0.f;
    }

    // write bf16 row into MFMA-layout LDS
    {
        uint4 p;
        p.x = pack2(o[0], o[1]);
        p.y = pack2(o[2], o[3]);
        p.z = pack2(o[4], o[5]);
        p.w = pack2(o[6], o[7]);
        *(uint4*)(&rows[sub * LDK2 + lane * 8]) = p;
        if (lane == 0) dinvv[sub] = di;
    }
    __syncthreads();

    // Phase B: wave w computes output cols [16w, 16w+16) for all 16 rows
    int w = tid >> 6;
    int l = tid & 63;
    int lo = l & 15, q = l >> 4;
    f4v acc = (f4v){0.f, 0.f, 0.f, 0.f};
#pragma unroll
    for (int ks = 0; ks < 4; ++ks) {
        s8v af = *(const s8v*)&rows[lo * LDK2 + ks * 32 + q * 8];
        s8v wf = *(const s8v*)&Wl2[(w * 16 + lo) * LDK2 + ks * 32 + q * 8];
        acc = __builtin_amdgcn_mfma_f32_16x16x32_bf16(wf, af, acc, 0, 0, 0);
    }
    int gn = blockIdx.x * 16 + lo;     // D[m][n]: n = row = lo, m = q*4+reg
    if (gn < N) {
        float dr = dinvv[lo];
        uint2 p;
        p.x = pack2(acc[0] * dr, acc[1] * dr);
        p.y = pack2(acc[2] * dr, acc[3] * dr);
        *(uint2*)(hs2 + (size_t)gn * 64 + w * 16 + q * 4) = p;
    }
}

// ---- aggregation: out[i] = dinv[i]*(hs[i] + sum_j hs[j]) + b ----

template <int C, bool RELU, bool OUTBF>
__global__ __launch_bounds__(256) void aggregate_k(const ushort* __restrict__ hs,
                                                   const float* __restrict__ dinv,
                                                   const int* __restrict__ rowptr,
                                                   const int* __restrict__ csr,
                                                   const float* __restrict__ bias,
                                                   void* __restrict__ out, int N) {
    constexpr int LANES = C / 8;       // 16B (8 bf16) per lane
    constexpr int NPB = 256 / LANES;
    int tid = threadIdx.x;
    int sub = tid / LANES;
    int lane = tid % LANES;
    int node = blockIdx.x * NPB + sub;
    if (node >= N) return;

    const uint4* h4 = (const uint4*)hs;
    float accA[8], accB[8];
    {
        uint4 v = h4[(size_t)node * LANES + lane];
        accA[0] = bflo(v.x); accA[1] = bfhi(v.x);
        accA[2] = bflo(v.y); accA[3] = bfhi(v.y);
        accA[4] = bflo(v.z); accA[5] = bfhi(v.z);
        accA[6] = bflo(v.w); accA[7] = bfhi(v.w);
    }
#pragma unroll
    for (int k = 0; k < 8; ++k) accB[k] = 0.f;

    int e = rowptr[node];
    int end = rowptr[node + 1];
    float di = dinv[node];
    for (; e + 8 <= end; e += 8) {
        int j[8];
#pragma unroll
        for (int k = 0; k < 8; ++k) j[k] = csr[e + k];
        uint4 v[8];
#pragma unroll
        for (int k = 0; k < 8; ++k) v[k] = h4[(size_t)j[k] * LANES + lane];
#pragma unroll
        for (int k = 0; k < 8; ++k) {
            float* a = (k & 1) ? accB : accA;
            a[0] += bflo(v[k].x); a[1] += bfhi(v[k].x);
            a[2] += bflo(v[k].y); a[3] += bfhi(v[k].y);
            a[4] += bflo(v[k].z); a[5] += bfhi(v[k].z);
            a[6] += bflo(v[k].w); a[7] += bfhi(v[k].w);
        }
    }
    if (e + 4 <= end) {
        int j0 = csr[e], j1 = csr[e + 1], j2 = csr[e + 2], j3 = csr[e + 3];
        uint4 v0 = h4[(size_t)j0 * LANES + lane];
        uint4 v1 = h4[(size_t)j1 * LANES + lane];
        uint4 v2 = h4[(size_t)j2 * LANES + lane];
        uint4 v3 = h4[(size_t)j3 * LANES + lane];
        accA[0] += bflo(v0.x) + bflo(v2.x); accA[1] += bfhi(v0.x) + bfhi(v2.x);
        accA[2] += bflo(v0.y) + bflo(v2.y); accA[3] += bfhi(v0.y) + bfhi(v2.y);
        accA[4] += bflo(v0.z) + bflo(v2.z); accA[5] += bfhi(v0.z) + bfhi(v2.z);
        accA[6] += bflo(v0.w) + bflo(v2.w); accA[7] += bfhi(v0.w) + bfhi(v2.w);
        accB[0] += bflo(v1.x) + bflo(v3.x); accB[1] += bfhi(v1.x) + bfhi(v3.x);
        accB[2] += bflo(v1.y) + bflo(v3.y); accB[3] += bfhi(v1.y) + bfhi(v3.y);
        accB[4] += bflo(v1.z) + bflo(v3.z); accB[5] += bfhi(v1.z) + bfhi(v3.z);
        accB[6] += bflo(v1.w) + bflo(v3.w); accB[7] += bfhi(v1.w) + bfhi(v3.w);
        e += 4;
    }
    for (; e < end; ++e) {
        uint4 v = h4[(size_t)csr[e] * LANES + lane];
        accA[0] += bflo(v.x); accA[1] += bfhi(v.x);
        accA[2] += bflo(v.y); accA[3] += bfhi(v.y);
        accA[4] += bflo(v.z); accA[5] += bfhi(v.z);
        accA[6] += bflo(v.w); accA[7] += bfhi(v.w);
    }

    const float4* b4 = (const float4*)(bias + lane * 8);
    float4 b0 = b4[0], b1 = b4[1];
    float o[8];
    o[0] = fmaf(di, accA[0] + accB[0], b0.x);
    o[1] = fmaf(di, accA[1] + accB[1], b0.y);
    o[2] = fmaf(di, accA[2] + accB[2], b0.z);
    o[3] = fmaf(di, accA[3] + accB[3], b0.w);
    o[4] = fmaf(di, accA[4] + accB[4], b1.x);
    o[5] = fmaf(di, accA[5] + accB[5], b1.y);
    o[6] = fmaf(di, accA[6] + accB[6], b1.z);
    o[7] = fmaf(di, accA[7] + accB[7], b1.w);
    if (RELU) {
#pragma unroll
        for (int k = 0; k < 8; ++k) o[k] = fmaxf(o[k], 0.f);
    }
    if (OUTBF) {
        uint4 p;
        p.x = pack2(o[0], o[1]);
        p.y = pack2(o[2], o[3]);
        p.z = pack2(o[4], o[5]);
        p.w = pack2(o[6], o[7]);
        *(uint4*)((ushort*)out + (size_t)node * C + lane * 8) = p;
    } else {
        float* op = (float*)out + (size_t)node * C + lane * 8;
        *(float4*)op = make_float4(o[0], o[1], o[2], o[3]);
        *(float4*)(op + 4) = make_float4(o[4], o[5], o[6], o[7]);
    }
}

// ---------------- launch ----------------

extern "C" void kernel_launch(void* const* d_in, const int* in_sizes, int n_in,
                              void* d_out, int out_size, void* d_ws, size_t ws_size,
                              hipStream_t stream) {
    const float* x  = (const float*)d_in[0];
    const int*   ei = (const int*)d_in[1];
    const float* W1 = (const float*)d_in[2];
    const float* b1 = (const float*)d_in[3];
    const float* W2 = (const float*)d_in[4];
    const float* b2 = (const float*)d_in[5];
    float* out = (float*)d_out;

    const int D = 128;
    int N = in_sizes[0] / D;
    int E = in_sizes[1] / 2;
    const int* src = ei;      // edge_index[0] (sources j)
    const int* dst = ei + E;  // edge_index[1] (targets i)

    int nbuck = (N + 255) >> BSHIFT;
    int PB = (E + PART_CH - 1) / PART_CH;
    int M1 = nbuck * PB;
    int G1 = (M1 + GS_CH - 1) / GS_CH;

    char* ws = (char*)d_ws;
    size_t off = 0;
    auto alloc = [&](size_t bytes) -> void* {
        void* p = ws + off;
        off += (bytes + 255) & ~(size_t)255;
        return p;
    };
    int*    cnt_blk = (int*)alloc((size_t)M1 * 4);
    int*    off_blk = (int*)alloc((size_t)M1 * 4);
    int*    gb      = (int*)alloc(2048);                    // scan blocksums (<=512)
    int*    rowptr  = (int*)alloc((size_t)(N + 1) * 4);
    float*  dinv    = (float*)alloc((size_t)N * 4);
    uint*   eb      = (uint*)alloc((size_t)E * 4);
    int*    csr     = (int*)alloc((size_t)E * 4);
    ushort* wt1     = (ushort*)alloc((size_t)128 * 128 * 2);
    ushort* wt2     = (ushort*)alloc((size_t)64 * 128 * 2);
    ushort* hs1     = (ushort*)alloc((size_t)N * 128 * 2);  // bf16 dinv*(x@W1)
    ushort* hs2     = (ushort*)alloc((size_t)N * 64 * 2);   // bf16 dinv*(h1a@W2)

    // CSR build: 1 histogram + exact-offset partition (LDS atomics only)
    hist2_k<<<PB, 256, 0, stream>>>(dst, E, nbuck, PB, cnt_blk);
    gs1_k<<<G1, 256, 0, stream>>>(cnt_blk, M1, gb);
    gs2_k<<<1, 512, 0, stream>>>(gb, G1);
    gs3_k<<<G1, 256, 0, stream>>>(cnt_blk, M1, gb, off_blk);
    part2_k<<<PB, 256, 0, stream>>>(src, dst, E, nbuck, PB, off_blk, eb);
    build_k<<<nbuck, 256, 0, stream>>>(eb, off_blk, PB, nbuck, N, E, rowptr, dinv, csr);
    // weights (single launch)
    wtrans_all_k<<<3, 64, 0, stream>>>(W1, W2, wt1, wt2);

    // layer 1 GEMM
    gemm_mfma<128, true><<<(N + 63) / 64, 256, 0, stream>>>(x, wt1, dinv, hs1, N);
    // fused: aggregate layer 1 + ReLU + GEMM 2  ->  hs2
    agg1_fused_k<<<(N + 15) / 16, 256, 0, stream>>>(hs1, dinv, rowptr, csr, b1, wt2, hs2, N);
    // aggregate layer 2 -> out (f32)
    aggregate_k<64, false, false><<<(N + 31) / 32, 256, 0, stream>>>(hs2, dinv, rowptr, csr, b2, out, N);
}